// Round 11
// baseline (40.706 us; speedup 1.0000x reference)
//
#include <hip/hip_runtime.h>

// CompressImageGPU: bilinear down(0.5, antialias) -> up -> +8x8 block noise -> clip,
// composed into one separable 6-tap conv on x.
// Round 11: persistent blocks (grid=512, 6 tiles each) with cross-tile software
// pipeline: hconv+ds_write tile t (regs loaded last iter) -> barrier -> ISSUE
// tile t+1 global loads into regs (no wait) -> v-pass compute+NT-store tile t.
// Read stream of t+1 overlaps write stream of t. __launch_bounds__(512,4)
// (VGPR cap 128) so 18 f32x4 of prefetch stay resident.

typedef float f32x4 __attribute__((ext_vector_type(4)));

namespace {
constexpr int IMG = 512;
constexpr int TY = 16;          // output rows per tile
constexpr int HROWS = TY + 6;   // 22
constexpr int TPB = 6;          // tiles per block
constexpr float I32 = 1.0f / 32.0f;
constexpr float I7  = 1.0f / 7.0f;
constexpr float I28 = 1.0f / 28.0f;
}

__device__ __forceinline__ f32x4 vfma(float w, f32x4 a, f32x4 acc) {
  acc.x = fmaf(w, a.x, acc.x); acc.y = fmaf(w, a.y, acc.y);
  acc.z = fmaf(w, a.z, acc.z); acc.w = fmaf(w, a.w, acc.w);
  return acc;
}
__device__ __forceinline__ f32x4 vmul(float w, f32x4 a) {
  f32x4 r; r.x = w * a.x; r.y = w * a.y; r.z = w * a.z; r.w = w * a.w;
  return r;
}

__global__ __launch_bounds__(512, 4) void compress_fused11_kernel(
    const float* __restrict__ x, const float* __restrict__ bn,
    float* __restrict__ out) {
  const int bid = blockIdx.x;               // 0..511
  const int cpx = gridDim.x >> 3;           // 64
  const int sw = (bid & 7) * cpx + (bid >> 3);  // bijective XCD chunking
  const int base = sw * TPB;                // tiles base..base+5 (tile = plane*32+ty)
  const int tid = threadIdx.x;
  const int cg = tid & 127;                 // column group: cols 4cg..4cg+3
  const int ts = tid >> 7;                  // row slot 0..3 (wave-uniform)
  const int gx0 = 4 * cg;

  __shared__ float H[HROWS][IMG];           // 44 KB

  const bool left  = (cg == 0);
  const bool right = (cg == 127);
  const int A0 = left ? 0 : (right ? IMG - 12 : gx0 - 4);  // f[i] = x[A0+i]

  auto hconv = [&](f32x4 qa, f32x4 qb, f32x4 qc) -> f32x4 {
    const float f0 = qa.x, f1 = qa.y, f2 = qa.z, f3 = qa.w;
    const float f4_ = qb.x, f5 = qb.y, f6 = qb.z, f7 = qb.w;
    const float f8 = qc.x, f9 = qc.y, f10 = qc.z, f11 = qc.w;
    f32x4 h;
    if (left) {  // f[i] = x[i]
      h.x = (3.f * f0 + 3.f * f1 + f2) * I7;
      h.y = 9*I28*f0 + (9*I28 + I32)*f1 + (3*I28 + 3*I32)*f2 + 3*I32*f3 + I32*f4_;
      h.z = 3*I28*f0 + (3*I28 + 3*I32)*f1 + (I28 + 9*I32)*f2 + 9*I32*f3 + 3*I32*f4_;
      h.w = (3.f*f1 + 9.f*f2 + 10.f*f3 + 6.f*f4_ + 3.f*f5 + f6) * I32;
    } else if (right) {  // f[i] = x[500+i]
      h.x = (f5 + 3.f*f6 + 6.f*f7 + 10.f*f8 + 9.f*f9 + 3.f*f10) * I32;
      h.y = 3*I32*f7 + 9*I32*f8 + (I28 + 9*I32)*f9 + (3*I28 + 3*I32)*f10 + 3*I28*f11;
      h.z = I32*f7 + 3*I32*f8 + (3*I28 + 3*I32)*f9 + (9*I28 + I32)*f10 + 9*I28*f11;
      h.w = (f9 + 3.f*f10 + 3.f*f11) * I7;
    } else {  // f[i] = x[gx0-4+i]
      h.x = (f1 + 3.f*f2 + 6.f*f3 + 10.f*f4_ + 9.f*f5 + 3.f*f6) * I32;
      h.y = (3.f*f3 + 9.f*f4_ + 10.f*f5 + 6.f*f6 + 3.f*f7 + f8) * I32;
      h.z = (f3 + 3.f*f4_ + 6.f*f5 + 10.f*f6 + 9.f*f7 + 3.f*f8) * I32;
      h.w = (3.f*f5 + 9.f*f6 + 10.f*f7 + 6.f*f8 + 3.f*f9 + f10) * I32;
    }
    return h;
  };

  // prefetch registers for one tile: rows r = ts + 4k, k = 0..5 (r < 22)
  f32x4 A[6], B[6], C[6];

  auto prefetch = [&](int logical) {
    const int plane = logical >> 5;
    const int y0 = (logical & 31) * TY;
    const float* xp = x + (size_t)plane * (IMG * IMG);
#pragma unroll
    for (int k = 0; k < 6; ++k) {
      const int r = ts + 4 * k;
      if (r < HROWS) {
        int g = y0 - 3 + r;
        g = max(0, min(IMG - 1, g));
        const f32x4* p = (const f32x4*)(xp + (size_t)g * IMG + A0);
        A[k] = p[0]; B[k] = p[1]; C[k] = p[2];
      }
    }
  };

  prefetch(base);

  for (int i = 0; i < TPB; ++i) {
    const int logical = base + i;
    const int plane = logical >> 5;
    const int ty = logical & 31;
    const int y0 = ty * TY;
    const int b = plane / 3;
    float* op = out + (size_t)plane * (IMG * IMG);

    __syncthreads();  // protect H from previous iteration's v-pass readers

    // ---- hconv + ds_write from prefetched regs ----
#pragma unroll
    for (int k = 0; k < 6; ++k) {
      const int r = ts + 4 * k;
      if (r < HROWS) *(f32x4*)&H[r][gx0] = hconv(A[k], B[k], C[k]);
    }
    __syncthreads();

    // ---- issue next tile's loads (in flight during v-pass below) ----
    if (i + 1 < TPB) prefetch(logical + 1);

    // ---- v-pass: 4 consecutive output rows from 10-row window ----
    const int wb = 4 * ts;  // H rows wb..wb+9
    const float nzv =
        (bn[(size_t)b * 4096 + ((y0 >> 3) + (ts >> 1)) * 64 + (cg >> 1)] - 0.5f) * 0.02f;
    const bool top = (y0 == 0 && ts == 0);
    const bool bot = (y0 == IMG - TY && ts == 3);
    const int gy0 = y0 + 4 * ts;

#define LDQ(j) (*(const f32x4*)&H[wb + (j)][gx0])
#define FINISH_STORE(o, ii)                                                    \
    {                                                                          \
      f32x4 v = o;                                                             \
      v.x = fminf(1.f, fmaxf(-1.f, v.x + nzv));                                \
      v.y = fminf(1.f, fmaxf(-1.f, v.y + nzv));                                \
      v.z = fminf(1.f, fmaxf(-1.f, v.z + nzv));                                \
      v.w = fminf(1.f, fmaxf(-1.f, v.w + nzv));                                \
      __builtin_nontemporal_store(v, (f32x4*)(op + (size_t)(gy0 + ii) * IMG + gx0)); \
    }

    const f32x4 q0 = LDQ(0), q1 = LDQ(1), q2 = LDQ(2);
    const f32x4 q3 = LDQ(3), q4 = LDQ(4), q5 = LDQ(5);

    f32x4 o0;
    if (top) {
      o0 = vfma(3*I7, q3, vfma(3*I7, q4, vmul(I7, q5)));
    } else {
      o0 = vfma(I32, q0, vfma(3*I32, q1, vfma(6*I32, q2,
           vfma(10*I32, q3, vfma(9*I32, q4, vmul(3*I32, q5))))));
    }
    FINISH_STORE(o0, 0)

    const f32x4 q6 = LDQ(6), q7 = LDQ(7);
    f32x4 o1, o2;
    if (top) {
      o1 = vfma(9*I28, q3, vfma(9*I28 + I32, q4,
           vfma(3*I28 + 3*I32, q5, vfma(3*I32, q6, vmul(I32, q7)))));
      o2 = vfma(3*I28, q3, vfma(3*I28 + 3*I32, q4,
           vfma(I28 + 9*I32, q5, vfma(9*I32, q6, vmul(3*I32, q7)))));
    } else if (bot) {
      o1 = vfma(3*I32, q2, vfma(9*I32, q3, vfma(I28 + 9*I32, q4,
           vfma(3*I28 + 3*I32, q5, vmul(3*I28, q6)))));
      o2 = vfma(I32, q2, vfma(3*I32, q3, vfma(3*I28 + 3*I32, q4,
           vfma(9*I28 + I32, q5, vmul(9*I28, q6)))));
    } else {
      o1 = vfma(3*I32, q2, vfma(9*I32, q3, vfma(10*I32, q4,
           vfma(6*I32, q5, vfma(3*I32, q6, vmul(I32, q7))))));
      o2 = vfma(I32, q2, vfma(3*I32, q3, vfma(6*I32, q4,
           vfma(10*I32, q5, vfma(9*I32, q6, vmul(3*I32, q7))))));
    }
    FINISH_STORE(o1, 1)
    FINISH_STORE(o2, 2)

    const f32x4 q8 = LDQ(8), q9 = LDQ(9);
    f32x4 o3;
    if (bot) {
      o3 = vfma(I7, q4, vfma(3*I7, q5, vmul(3*I7, q6)));
    } else {
      o3 = vfma(3*I32, q4, vfma(9*I32, q5, vfma(10*I32, q6,
           vfma(6*I32, q7, vfma(3*I32, q8, vmul(I32, q9))))));
    }
    FINISH_STORE(o3, 3)
#undef FINISH_STORE
#undef LDQ
  }
}

extern "C" void kernel_launch(void* const* d_in, const int* in_sizes, int n_in,
                              void* d_out, int out_size, void* d_ws, size_t ws_size,
                              hipStream_t stream) {
  const float* x  = (const float*)d_in[0];
  const float* bn = (const float*)d_in[1];
  float* out = (float*)d_out;

  const int n_planes = in_sizes[0] / (IMG * IMG);    // B*C = 96
  const int n_tiles = (IMG / TY) * n_planes;         // 3072
  const int nwg = n_tiles / TPB;                     // 512 (div by 8)
  compress_fused11_kernel<<<dim3(nwg), dim3(512), 0, stream>>>(x, bn, out);
}

// Round 12
// 40.258 us; speedup vs baseline: 1.0111x; 1.0111x over previous
//
#include <hip/hip_runtime.h>

// CompressImageGPU: bilinear down(0.5, antialias) -> up -> +8x8 block noise -> clip,
// composed into one separable 6-tap conv on x.
// Round 12: NO LDS / NO BARRIER rolling-window streaming. Each thread owns
// 4 cols x 16 output rows of one full-width strip: streams 22 input rows
// (double-buffered 2-row loads always in flight), h-conv into an 8-deep rolling
// register window, emits 2 output rows per step. Redundancy 1.375x (vs R8's
// fatal 2.5x), per-wave 1KB contiguous loads AND stores every step, waves fully
// decoupled -> read/write streams continuously interleaved. Cached stores.

typedef float f32x4 __attribute__((ext_vector_type(4)));

namespace {
constexpr int IMG = 512;
constexpr int TY = 16;          // output rows per strip
constexpr float I32 = 1.0f / 32.0f;
constexpr float I7  = 1.0f / 7.0f;
constexpr float I28 = 1.0f / 28.0f;
}

__device__ __forceinline__ f32x4 vfma(float w, f32x4 a, f32x4 acc) {
  acc.x = fmaf(w, a.x, acc.x); acc.y = fmaf(w, a.y, acc.y);
  acc.z = fmaf(w, a.z, acc.z); acc.w = fmaf(w, a.w, acc.w);
  return acc;
}
__device__ __forceinline__ f32x4 vmul(float w, f32x4 a) {
  f32x4 r; r.x = w * a.x; r.y = w * a.y; r.z = w * a.z; r.w = w * a.w;
  return r;
}

__global__ __launch_bounds__(128, 4) void compress_fused12_kernel(
    const float* __restrict__ x, const float* __restrict__ bn,
    float* __restrict__ out) {
  // XCD-chunked bijective swizzle: 3072 strips, XCD x gets strips [x*384,(x+1)*384)
  const int bid = blockIdx.x;
  const int sid = (bid & 7) * (gridDim.x >> 3) + (bid >> 3);
  const int plane = sid >> 5;       // 0..95
  const int st = sid & 31;          // strip 0..31 within plane
  const int y0 = st * TY;
  const int b = plane / 3;
  const int cg = threadIdx.x;       // 0..127, cols 4cg..4cg+3
  const int gx0 = 4 * cg;

  const float* xp = x + (size_t)plane * (IMG * IMG);
  float* op = out + (size_t)plane * (IMG * IMG);

  // two 8-row noise bands cover rows y0..y0+15
  const float nz0 = (bn[(size_t)b * 4096 + (2 * st) * 64 + (cg >> 1)] - 0.5f) * 0.02f;
  const float nz1 = (bn[(size_t)b * 4096 + (2 * st + 1) * 64 + (cg >> 1)] - 0.5f) * 0.02f;

  const bool left  = (cg == 0);
  const bool right = (cg == 127);
  const int A0 = left ? 0 : (right ? IMG - 12 : gx0 - 4);  // f[i] = x[A0+i]

  f32x4 buf[4][3];  // all indices compile-time after inlining/unroll
  f32x4 h[8];       // rolling window: h[p] = hconv(input row g(2t+p))

  auto LOAD = [&](int j, int s) {
    int g = y0 - 3 + j;
    g = max(0, min(IMG - 1, g));
    const f32x4* p = (const f32x4*)(xp + (size_t)g * IMG + A0);
    buf[s][0] = p[0]; buf[s][1] = p[1]; buf[s][2] = p[2];
  };

  auto hconv = [&](const f32x4& qa, const f32x4& qb, const f32x4& qc) -> f32x4 {
    const float f0 = qa.x, f1 = qa.y, f2 = qa.z, f3 = qa.w;
    const float f4_ = qb.x, f5 = qb.y, f6 = qb.z, f7 = qb.w;
    const float f8 = qc.x, f9 = qc.y, f10 = qc.z, f11 = qc.w;
    f32x4 r;
    if (left) {  // f[i] = x[i]
      r.x = (3.f * f0 + 3.f * f1 + f2) * I7;
      r.y = 9*I28*f0 + (9*I28 + I32)*f1 + (3*I28 + 3*I32)*f2 + 3*I32*f3 + I32*f4_;
      r.z = 3*I28*f0 + (3*I28 + 3*I32)*f1 + (I28 + 9*I32)*f2 + 9*I32*f3 + 3*I32*f4_;
      r.w = (3.f*f1 + 9.f*f2 + 10.f*f3 + 6.f*f4_ + 3.f*f5 + f6) * I32;
    } else if (right) {  // f[i] = x[500+i]
      r.x = (f5 + 3.f*f6 + 6.f*f7 + 10.f*f8 + 9.f*f9 + 3.f*f10) * I32;
      r.y = 3*I32*f7 + 9*I32*f8 + (I28 + 9*I32)*f9 + (3*I28 + 3*I32)*f10 + 3*I28*f11;
      r.z = I32*f7 + 3*I32*f8 + (3*I28 + 3*I32)*f9 + (9*I28 + I32)*f10 + 9*I28*f11;
      r.w = (f9 + 3.f*f10 + 3.f*f11) * I7;
    } else {  // f[i] = x[gx0-4+i]
      r.x = (f1 + 3.f*f2 + 6.f*f3 + 10.f*f4_ + 9.f*f5 + 3.f*f6) * I32;
      r.y = (3.f*f3 + 9.f*f4_ + 10.f*f5 + 6.f*f6 + 3.f*f7 + f8) * I32;
      r.z = (f3 + 3.f*f4_ + 6.f*f5 + 10.f*f6 + 9.f*f7 + 3.f*f8) * I32;
      r.w = (3.f*f5 + 9.f*f6 + 10.f*f7 + 6.f*f8 + 3.f*f9 + f10) * I32;
    }
    return r;
  };

  // ---- prologue: fill window j=0..7; leave j=8,9 in flight (slots 0,1) ----
  LOAD(0, 0) ; LOAD(1, 1); LOAD(2, 2); LOAD(3, 3);
  h[0] = hconv(buf[0][0], buf[0][1], buf[0][2]);
  h[1] = hconv(buf[1][0], buf[1][1], buf[1][2]);
  LOAD(4, 0); LOAD(5, 1);
  h[2] = hconv(buf[2][0], buf[2][1], buf[2][2]);
  h[3] = hconv(buf[3][0], buf[3][1], buf[3][2]);
  LOAD(6, 2); LOAD(7, 3);
  h[4] = hconv(buf[0][0], buf[0][1], buf[0][2]);
  h[5] = hconv(buf[1][0], buf[1][1], buf[1][2]);
  LOAD(8, 0); LOAD(9, 1);
  h[6] = hconv(buf[2][0], buf[2][1], buf[2][2]);
  h[7] = hconv(buf[3][0], buf[3][1], buf[3][2]);

#define FINISH_STORE(o, gy, NZ)                                                \
  {                                                                            \
    f32x4 v = o;                                                               \
    v.x = fminf(1.f, fmaxf(-1.f, v.x + NZ));                                   \
    v.y = fminf(1.f, fmaxf(-1.f, v.y + NZ));                                   \
    v.z = fminf(1.f, fmaxf(-1.f, v.z + NZ));                                   \
    v.w = fminf(1.f, fmaxf(-1.f, v.w + NZ));                                   \
    *(f32x4*)(op + (size_t)(gy) * IMG + gx0) = v;                              \
  }

#pragma unroll
  for (int t = 0; t < 8; ++t) {
    // ---- emit output rows y0+2t (even) and y0+2t+1 (odd) ----
    const float nzv = (t < 4) ? nz0 : nz1;
    const int gy = y0 + 2 * t;
    f32x4 oE, oO;
    if (st == 0 && t == 0) {
      // window rows [0,0,0,0,1,2,3,4]
      oE = vfma(3*I7, h[3], vfma(3*I7, h[4], vmul(I7, h[5])));
      oO = vfma(9*I28, h[3], vfma(9*I28 + I32, h[4],
           vfma(3*I28 + 3*I32, h[5], vfma(3*I32, h[6], vmul(I32, h[7])))));
    } else if (st == 0 && t == 1) {
      // window rows [0,0,1,2,3,4,5,6]
      oE = vfma(3*I28, h[1], vfma(3*I28 + 3*I32, h[2],
           vfma(I28 + 9*I32, h[3], vfma(9*I32, h[4], vmul(3*I32, h[5])))));
      oO = vfma(3*I32, h[2], vfma(9*I32, h[3], vfma(10*I32, h[4],
           vfma(6*I32, h[5], vfma(3*I32, h[6], vmul(I32, h[7]))))));
    } else if (st == 31 && t == 6) {
      // window rows [505..511,511]
      oE = vfma(I32, h[0], vfma(3*I32, h[1], vfma(6*I32, h[2],
           vfma(10*I32, h[3], vfma(9*I32, h[4], vmul(3*I32, h[5]))))));
      oO = vfma(3*I32, h[2], vfma(9*I32, h[3], vfma(I28 + 9*I32, h[4],
           vfma(3*I28 + 3*I32, h[5], vmul(3*I28, h[6])))));
    } else if (st == 31 && t == 7) {
      // window rows [507,508,509,510,511,511,511,511]
      oE = vfma(I32, h[0], vfma(3*I32, h[1], vfma(3*I28 + 3*I32, h[2],
           vfma(9*I28 + I32, h[3], vmul(9*I28, h[4])))));
      oO = vfma(I7, h[2], vfma(3*I7, h[3], vmul(3*I7, h[4])));
    } else {
      oE = vfma(I32, h[0], vfma(3*I32, h[1], vfma(6*I32, h[2],
           vfma(10*I32, h[3], vfma(9*I32, h[4], vmul(3*I32, h[5]))))));
      oO = vfma(3*I32, h[2], vfma(9*I32, h[3], vfma(10*I32, h[4],
           vfma(6*I32, h[5], vfma(3*I32, h[6], vmul(I32, h[7]))))));
    }
    FINISH_STORE(oE, gy, nzv)
    FINISH_STORE(oO, gy + 1, nzv)

    // ---- advance stream: issue next loads, consume in-flight pair ----
    if (t < 7) {
      if (t < 6) {
        if ((t & 1) == 0) { LOAD(2 * t + 10, 2); LOAD(2 * t + 11, 3); }
        else              { LOAD(2 * t + 10, 0); LOAD(2 * t + 11, 1); }
      }
      h[0] = h[2]; h[1] = h[3]; h[2] = h[4]; h[3] = h[5]; h[4] = h[6]; h[5] = h[7];
      if ((t & 1) == 0) {
        h[6] = hconv(buf[0][0], buf[0][1], buf[0][2]);
        h[7] = hconv(buf[1][0], buf[1][1], buf[1][2]);
      } else {
        h[6] = hconv(buf[2][0], buf[2][1], buf[2][2]);
        h[7] = hconv(buf[3][0], buf[3][1], buf[3][2]);
      }
    }
  }
#undef FINISH_STORE
}

extern "C" void kernel_launch(void* const* d_in, const int* in_sizes, int n_in,
                              void* d_out, int out_size, void* d_ws, size_t ws_size,
                              hipStream_t stream) {
  const float* x  = (const float*)d_in[0];
  const float* bn = (const float*)d_in[1];
  float* out = (float*)d_out;

  const int n_planes = in_sizes[0] / (IMG * IMG);  // B*C = 96
  const int nwg = (IMG / TY) * n_planes;           // 32 * 96 = 3072 (div by 8)
  compress_fused12_kernel<<<dim3(nwg), dim3(128), 0, stream>>>(x, bn, out);
}